// Round 11
// baseline (270.724 us; speedup 1.0000x reference)
//
#include <hip/hip_runtime.h>

#define NNODES 100000
#define NEDGES 1600000
#define BSHIFT 7
#define NB 782            // buckets of 128 nodes: bucket = dst >> 7
#define CAP 2560          // padded per-bucket capacity (mean 2048, +11 sigma)
#define EBLOCKS 391       // edge-scatter blocks (4096 edges each)
#define GEMM_BLOCKS 1563  // (NNODES + 63) / 64
#define QBLOCKS 6250      // z1 quantize blocks (12.8M bytes / 2048)

typedef _Float16 f16;
typedef _Float16 v8h __attribute__((ext_vector_type(8)));
typedef float v4f __attribute__((ext_vector_type(4)));

// u16-packed integer accumulate of 8 biased-uint8 channels (uint2 = 8 bytes).
// Each u32 acc holds two 16-bit channel sums; deg<=~60 * 255 < 2^16 -> no carry.
__device__ inline void accu(uint2 u, unsigned& A, unsigned& B,
                            unsigned& C, unsigned& D) {
    A += u.x & 0x00FF00FFu;
    B += (u.x >> 8) & 0x00FF00FFu;
    C += u.y & 0x00FF00FFu;
    D += (u.y >> 8) & 0x00FF00FFu;
}

// ---------------------------------------------------------------------------
// Init: bucket cursors + weight transpose/convert + zero column-max slots.
// ---------------------------------------------------------------------------
__global__ __launch_bounds__(256) void init_k(int* __restrict__ bcur,
                                              const float* __restrict__ W1,
                                              f16* __restrict__ W1t,
                                              const float* __restrict__ W2,
                                              f16* __restrict__ W2t,
                                              int* __restrict__ colmax1,
                                              int* __restrict__ colmax2) {
    int t = blockIdx.x * 256 + threadIdx.x;
    if (t < NB) bcur[t] = t * CAP;
    if (t >= 800 && t < 928) colmax1[t - 800] = 0;
    if (t >= 928 && t < 992) colmax2[t - 928] = 0;
    int u = t - 1024;
    if (u >= 0) {
        if (u < 128 * 128) {
            int k = u >> 7, n = u & 127;
            W1t[n * 128 + k] = (f16)W1[k * 128 + n];
        } else if (u < 128 * 128 + 128 * 64) {
            int v = u - 128 * 128;
            int k = v >> 6, n = v & 63;
            W2t[n * 128 + k] = (f16)W2[k * 64 + n];
        }
    }
}

// ---------------------------------------------------------------------------
// Fused: edge scatter into bucket-padded ebuf (blocks 0..EBLOCKS-1) +
// layer-1 MFMA GEMM (remaining blocks). z1 written as f16 + per-COLUMN |max|
// (LDS-reduced, then global atomicMax). Column scales enable integer
// segment-sums in the gather (the round-9 VALU bottleneck).
// ebuf entry packed 4B: src | (dst&127)<<24  (src < 2^17).
// ---------------------------------------------------------------------------
__global__ __launch_bounds__(256) void scatter_gemm1(
    const int* __restrict__ src, const int* __restrict__ dst,
    int* __restrict__ bcur, int* __restrict__ ebuf,
    const float* __restrict__ feat, const f16* __restrict__ W1t,
    f16* __restrict__ z1f, int* __restrict__ colmax1) {
    constexpr int PITCH = 136;
    __shared__ __align__(16) char smem[128 * PITCH * 2];  // 34816 B
    __shared__ int lmax[128];
    int tid = threadIdx.x;

    if (blockIdx.x < EBLOCKS) {
        int* h = (int*)smem;
        int* base_s = ((int*)smem) + 1024;
        for (int i = tid; i < NB; i += 256) h[i] = 0;
        __syncthreads();
        int base = blockIdx.x * 4096;
        int d[16], sv[16];
        for (int k = 0; k < 16; k++) {
            int e = base + k * 256 + tid;
            if (e < NEDGES) {
                d[k] = dst[e];
                sv[k] = src[e];
                atomicAdd(&h[d[k] >> BSHIFT], 1);
            } else {
                d[k] = -1;
            }
        }
        __syncthreads();
        for (int i = tid; i < NB; i += 256) {
            int c = h[i];
            if (c) base_s[i] = atomicAdd(&bcur[i], c);
            h[i] = 0;
        }
        __syncthreads();
        for (int k = 0; k < 16; k++) {
            if (d[k] >= 0) {
                int b = d[k] >> BSHIFT;
                int slot = atomicAdd(&h[b], 1);
                ebuf[base_s[b] + slot] = sv[k] | ((d[k] & 127) << 24);
            }
        }
        return;
    }

    // ---- GEMM-1 branch: z1f = f16(feat) @ W1t^T + column maxes ----
    f16* wlds = (f16*)smem;
    for (int c = tid; c < 128 * 16; c += 256) {
        int n = c >> 4;
        int kc = c & 15;
        *(v8h*)&wlds[n * PITCH + kc * 8] = *(const v8h*)&W1t[n * 128 + kc * 8];
    }
    if (tid < 128) lmax[tid] = 0;
    __syncthreads();

    int wave = tid >> 6, lane = tid & 63, quad = lane >> 4, l16 = lane & 15;
    int m0 = (blockIdx.x - EBLOCKS) * 64 + wave * 16;
    bool valid = (m0 < NNODES);  // wave's 16 rows all in or all out (16|NNODES)
    int mrow = m0 + l16;
    if (mrow >= NNODES) mrow = NNODES - 1;  // clamp loads; no early return
                                            // (barrier below needs all waves)

    v8h a[4];
    const float* arow = feat + (long)mrow * 128 + quad * 8;
#pragma unroll
    for (int kb = 0; kb < 4; kb++) {
        float4 f0 = *(const float4*)(arow + kb * 32);
        float4 f1 = *(const float4*)(arow + kb * 32 + 4);
        v8h t = {(f16)f0.x, (f16)f0.y, (f16)f0.z, (f16)f0.w,
                 (f16)f1.x, (f16)f1.y, (f16)f1.z, (f16)f1.w};
        a[kb] = t;
    }

#pragma unroll
    for (int nt = 0; nt < 8; nt++) {
        v4f c4 = {0.f, 0.f, 0.f, 0.f};
        const f16* brow = &wlds[(nt * 16 + l16) * PITCH + quad * 8];
#pragma unroll
        for (int kb = 0; kb < 4; kb++) {
            v8h b = *(const v8h*)(brow + kb * 32);
            c4 = __builtin_amdgcn_mfma_f32_16x16x32_f16(a[kb], b, c4, 0, 0, 0);
        }
        int n = nt * 16 + l16;
        if (valid) {
#pragma unroll
            for (int r = 0; r < 4; r++)
                z1f[(long)(m0 + quad * 4 + r) * 128 + n] = (f16)c4[r];
        }
        float m = fmaxf(fmaxf(fabsf(c4[0]), fabsf(c4[1])),
                        fmaxf(fabsf(c4[2]), fabsf(c4[3])));
        m = fmaxf(m, __shfl_xor(m, 16));
        m = fmaxf(m, __shfl_xor(m, 32));
        if (quad == 0) atomicMax(&lmax[n], __float_as_int(m));
    }
    __syncthreads();
    if (tid < 128) atomicMax(&colmax1[tid], lmax[tid]);
}

// ---------------------------------------------------------------------------
// Fused launch: per-bucket CSR fill (blocks < NB, csr4 only — no scale
// packing) + z1 f16 -> biased-uint8 quantize with column scales (remaining
// QBLOCKS blocks; independent work, same dependency set).
// ---------------------------------------------------------------------------
__global__ __launch_bounds__(256) void fill_quant(const int* __restrict__ ebuf,
                                                  const int* __restrict__ bcur,
                                                  int* __restrict__ begs,
                                                  int* __restrict__ ends,
                                                  int* __restrict__ csr4,
                                                  const f16* __restrict__ z1f,
                                                  const int* __restrict__ colmax1,
                                                  unsigned char* __restrict__ z1q) {
    __shared__ int lc[128];
    __shared__ int ls[256];
    __shared__ float rs[128];
    int tid = threadIdx.x;

    if (blockIdx.x < NB) {
        int b = blockIdx.x;
        if (tid < 128) lc[tid] = 0;
        __syncthreads();
        int ebeg = b * CAP;
        int eend = bcur[b];
        for (int e = ebeg + tid; e < eend; e += 256)
            atomicAdd(&lc[((unsigned)ebuf[e]) >> 24], 1);
        __syncthreads();
        int cnt = (tid < 128) ? lc[tid] : 0;
        ls[tid] = cnt;
        __syncthreads();
        for (int off = 1; off < 256; off <<= 1) {
            int t = (tid >= off) ? ls[tid - off] : 0;
            __syncthreads();
            ls[tid] += t;
            __syncthreads();
        }
        int excl = ls[tid] - cnt;
        int node = (b << BSHIFT) + tid;
        if (tid < 128 && node < NNODES) {
            begs[node] = ebeg + excl;
            ends[node] = ebeg + excl + cnt;
        }
        if (tid < 128) { ls[tid] = excl; lc[tid] = 0; }
        __syncthreads();
        for (int e = ebeg + tid; e < eend; e += 256) {
            int p = ebuf[e];
            int dloc = ((unsigned)p) >> 24;
            int slot = atomicAdd(&lc[dloc], 1);
            csr4[ebeg + ls[dloc] + slot] = p & 0xFFFFFF;
        }
        return;
    }

    // ---- quantize branch: 8 elems/thread, 2048/block ----
    if (tid < 128) {
        float m = __int_as_float(colmax1[tid]);
        rs[tid] = (m > 0.f) ? 127.f / m : 0.f;
    }
    __syncthreads();
    long base = (long)(blockIdx.x - NB) * 2048 + tid * 8;
    v8h v = *(const v8h*)&z1f[base];
    int c0 = (int)(base & 127);
    unsigned q[8];
#pragma unroll
    for (int j = 0; j < 8; j++)
        q[j] = (unsigned)((int)rintf((float)v[j] * rs[c0 + j]) + 128);
    uint2 o;
    o.x = q[0] | (q[1] << 8) | (q[2] << 16) | (q[3] << 24);
    o.y = q[4] | (q[5] << 8) | (q[6] << 16) | (q[7] << 24);
    *(uint2*)&z1q[base] = o;
}

// ---------------------------------------------------------------------------
// Layer-1 gather -> h1 (f16), barrier-free, INTEGER accumulation. 16-lane
// subgroup per node; per edge: csr4 4B broadcast + 8B row chunk + 10 packed
// int ops (vs round-9's 16 float ops + scale loads). Decode once per node:
// sum_c = colscale_c * (isum_c - 128*cnt), cnt = deg+1.
// ---------------------------------------------------------------------------
__global__ __launch_bounds__(256, 8) void gather128_h1(
    const unsigned char* __restrict__ z,  // z1q, 128 B rows
    const int* __restrict__ csr,
    const int* __restrict__ begs, const int* __restrict__ ends,
    const int* __restrict__ colmax1,
    const float* __restrict__ b1,
    f16* __restrict__ h1) {
    int tid = threadIdx.x;
    int c = tid & 15;                         // channel block: c*8 .. c*8+7
    int node = blockIdx.x * 16 + (tid >> 4);  // 6250*16 == NNODES exactly

    int beg = begs[node];
    int end = ends[node];
    unsigned coff = (unsigned)c << 3;

    unsigned A = 0, B = 0, C = 0, D = 0;
    {
        uint2 u = *(const uint2*)(z + (((unsigned)node) << 7) + coff);
        accu(u, A, B, C, D);
    }

    int e = beg;
    while (__any(e < end)) {
        int i0 = 0, i1 = 0, i2 = 0, i3 = 0, i4 = 0, i5 = 0, i6 = 0, i7 = 0;
        if (e     < end) i0 = csr[e];
        if (e + 1 < end) i1 = csr[e + 1];
        if (e + 2 < end) i2 = csr[e + 2];
        if (e + 3 < end) i3 = csr[e + 3];
        if (e + 4 < end) i4 = csr[e + 4];
        if (e + 5 < end) i5 = csr[e + 5];
        if (e + 6 < end) i6 = csr[e + 6];
        if (e + 7 < end) i7 = csr[e + 7];
        uint2 u0 = make_uint2(0, 0), u1 = make_uint2(0, 0);
        uint2 u2 = make_uint2(0, 0), u3 = make_uint2(0, 0);
        uint2 u4 = make_uint2(0, 0), u5 = make_uint2(0, 0);
        uint2 u6 = make_uint2(0, 0), u7 = make_uint2(0, 0);
        if (e     < end) u0 = *(const uint2*)(z + (((unsigned)i0) << 7) + coff);
        if (e + 1 < end) u1 = *(const uint2*)(z + (((unsigned)i1) << 7) + coff);
        if (e + 2 < end) u2 = *(const uint2*)(z + (((unsigned)i2) << 7) + coff);
        if (e + 3 < end) u3 = *(const uint2*)(z + (((unsigned)i3) << 7) + coff);
        if (e + 4 < end) u4 = *(const uint2*)(z + (((unsigned)i4) << 7) + coff);
        if (e + 5 < end) u5 = *(const uint2*)(z + (((unsigned)i5) << 7) + coff);
        if (e + 6 < end) u6 = *(const uint2*)(z + (((unsigned)i6) << 7) + coff);
        if (e + 7 < end) u7 = *(const uint2*)(z + (((unsigned)i7) << 7) + coff);
        accu(u0, A, B, C, D); accu(u1, A, B, C, D);
        accu(u2, A, B, C, D); accu(u3, A, B, C, D);
        accu(u4, A, B, C, D); accu(u5, A, B, C, D);
        accu(u6, A, B, C, D); accu(u7, A, B, C, D);
        e += 8;
    }

    int cnt = end - beg + 1;
    int b128 = 128 * cnt;
    int is[8];
    is[0] = (int)(A & 0xFFFFu); is[2] = (int)(A >> 16);
    is[1] = (int)(B & 0xFFFFu); is[3] = (int)(B >> 16);
    is[4] = (int)(C & 0xFFFFu); is[6] = (int)(C >> 16);
    is[5] = (int)(D & 0xFFFFu); is[7] = (int)(D >> 16);
    float inv = 1.0f / (float)cnt;
    float4 bb0 = ((const float4*)b1)[c * 2];
    float4 bb1 = ((const float4*)b1)[c * 2 + 1];
    float bv[8] = {bb0.x, bb0.y, bb0.z, bb0.w, bb1.x, bb1.y, bb1.z, bb1.w};
    v8h o;
#pragma unroll
    for (int j = 0; j < 8; j++) {
        float s = __int_as_float(colmax1[c * 8 + j]) * (1.0f / 127.0f) * inv;
        o[j] = (f16)fmaxf((float)(is[j] - b128) * s + bv[j], 0.f);
    }
    *(v8h*)&h1[(long)node * 128 + c * 8] = o;
}

// ---------------------------------------------------------------------------
// Layer-2 projection: z2f = f16(h1 @ W2t^T) + column maxes (same two-pass
// column-scale scheme as layer 1).
// ---------------------------------------------------------------------------
__global__ __launch_bounds__(256) void gemm2_k(
    const f16* __restrict__ h1,       // [NNODES,128]
    const f16* __restrict__ W2t,      // [64,128]
    f16* __restrict__ z2f,            // [NNODES,64]
    int* __restrict__ colmax2) {
    constexpr int PITCH = 136;
    __shared__ f16 wlds[64 * PITCH];  // 17408 B
    __shared__ int lmax[64];
    int tid = threadIdx.x;
    for (int c = tid; c < 64 * 16; c += 256) {
        int n = c >> 4;
        int kc = c & 15;
        *(v8h*)&wlds[n * PITCH + kc * 8] = *(const v8h*)&W2t[n * 128 + kc * 8];
    }
    if (tid < 64) lmax[tid] = 0;
    __syncthreads();

    int wave = tid >> 6, lane = tid & 63, quad = lane >> 4, l16 = lane & 15;
    int m0 = blockIdx.x * 64 + wave * 16;
    bool valid = (m0 < NNODES);
    int mrow = m0 + l16;
    if (mrow >= NNODES) mrow = NNODES - 1;

    v8h a[4];
    const f16* arow = h1 + (long)mrow * 128 + quad * 8;
#pragma unroll
    for (int kb = 0; kb < 4; kb++) a[kb] = *(const v8h*)(arow + kb * 32);

#pragma unroll
    for (int nt = 0; nt < 4; nt++) {
        v4f c4 = {0.f, 0.f, 0.f, 0.f};
        const f16* brow = &wlds[(nt * 16 + l16) * PITCH + quad * 8];
#pragma unroll
        for (int kb = 0; kb < 4; kb++) {
            v8h b = *(const v8h*)(brow + kb * 32);
            c4 = __builtin_amdgcn_mfma_f32_16x16x32_f16(a[kb], b, c4, 0, 0, 0);
        }
        int n = nt * 16 + l16;
        if (valid) {
#pragma unroll
            for (int r = 0; r < 4; r++)
                z2f[(long)(m0 + quad * 4 + r) * 64 + n] = (f16)c4[r];
        }
        float m = fmaxf(fmaxf(fabsf(c4[0]), fabsf(c4[1])),
                        fmaxf(fabsf(c4[2]), fabsf(c4[3])));
        m = fmaxf(m, __shfl_xor(m, 16));
        m = fmaxf(m, __shfl_xor(m, 32));
        if (quad == 0) atomicMax(&lmax[n], __float_as_int(m));
    }
    __syncthreads();
    if (tid < 64) atomicMax(&colmax2[tid], lmax[tid]);
}

// ---------------------------------------------------------------------------
// z2 f16 -> biased-uint8 quantize with column scales. 3125 blocks.
// ---------------------------------------------------------------------------
__global__ __launch_bounds__(256) void quant_z2(const f16* __restrict__ z2f,
                                                const int* __restrict__ colmax2,
                                                unsigned char* __restrict__ z2q) {
    __shared__ float rs[64];
    int tid = threadIdx.x;
    if (tid < 64) {
        float m = __int_as_float(colmax2[tid]);
        rs[tid] = (m > 0.f) ? 127.f / m : 0.f;
    }
    __syncthreads();
    long base = (long)blockIdx.x * 2048 + tid * 8;
    v8h v = *(const v8h*)&z2f[base];
    int c0 = (int)(base & 63);
    unsigned q[8];
#pragma unroll
    for (int j = 0; j < 8; j++)
        q[j] = (unsigned)((int)rintf((float)v[j] * rs[c0 + j]) + 128);
    uint2 o;
    o.x = q[0] | (q[1] << 8) | (q[2] << 16) | (q[3] << 24);
    o.y = q[4] | (q[5] << 8) | (q[6] << 16) | (q[7] << 24);
    *(uint2*)&z2q[base] = o;
}

// ---------------------------------------------------------------------------
// Layer-2 gather+normalize, INTEGER accumulation, fp32 out. 8-lane subgroup
// per node (64B row = 1 line); no per-edge scale loads at all.
// ---------------------------------------------------------------------------
__global__ __launch_bounds__(256, 8) void gather64(
    const unsigned char* __restrict__ z, const int* __restrict__ csr,
    const int* __restrict__ begs, const int* __restrict__ ends,
    const int* __restrict__ colmax2,
    const float* __restrict__ bias, float4* __restrict__ out) {
    int tid = threadIdx.x;
    int c = tid & 7;                          // channel block: c*8..c*8+7
    int node = blockIdx.x * 32 + (tid >> 3);  // 3125*32 == NNODES exactly

    int beg = begs[node];
    int end = ends[node];
    unsigned coff = (unsigned)c << 3;

    unsigned A = 0, B = 0, C = 0, D = 0;
    {
        uint2 u = *(const uint2*)(z + (((unsigned)node) << 6) + coff);
        accu(u, A, B, C, D);
    }

    int e = beg;
    while (__any(e < end)) {
        int i0 = 0, i1 = 0, i2 = 0, i3 = 0, i4 = 0, i5 = 0, i6 = 0, i7 = 0;
        if (e     < end) i0 = csr[e];
        if (e + 1 < end) i1 = csr[e + 1];
        if (e + 2 < end) i2 = csr[e + 2];
        if (e + 3 < end) i3 = csr[e + 3];
        if (e + 4 < end) i4 = csr[e + 4];
        if (e + 5 < end) i5 = csr[e + 5];
        if (e + 6 < end) i6 = csr[e + 6];
        if (e + 7 < end) i7 = csr[e + 7];
        uint2 u0 = make_uint2(0, 0), u1 = make_uint2(0, 0);
        uint2 u2 = make_uint2(0, 0), u3 = make_uint2(0, 0);
        uint2 u4 = make_uint2(0, 0), u5 = make_uint2(0, 0);
        uint2 u6 = make_uint2(0, 0), u7 = make_uint2(0, 0);
        if (e     < end) u0 = *(const uint2*)(z + (((unsigned)i0) << 6) + coff);
        if (e + 1 < end) u1 = *(const uint2*)(z + (((unsigned)i1) << 6) + coff);
        if (e + 2 < end) u2 = *(const uint2*)(z + (((unsigned)i2) << 6) + coff);
        if (e + 3 < end) u3 = *(const uint2*)(z + (((unsigned)i3) << 6) + coff);
        if (e + 4 < end) u4 = *(const uint2*)(z + (((unsigned)i4) << 6) + coff);
        if (e + 5 < end) u5 = *(const uint2*)(z + (((unsigned)i5) << 6) + coff);
        if (e + 6 < end) u6 = *(const uint2*)(z + (((unsigned)i6) << 6) + coff);
        if (e + 7 < end) u7 = *(const uint2*)(z + (((unsigned)i7) << 6) + coff);
        accu(u0, A, B, C, D); accu(u1, A, B, C, D);
        accu(u2, A, B, C, D); accu(u3, A, B, C, D);
        accu(u4, A, B, C, D); accu(u5, A, B, C, D);
        accu(u6, A, B, C, D); accu(u7, A, B, C, D);
        e += 8;
    }

    int cnt = end - beg + 1;
    int b128 = 128 * cnt;
    int is[8];
    is[0] = (int)(A & 0xFFFFu); is[2] = (int)(A >> 16);
    is[1] = (int)(B & 0xFFFFu); is[3] = (int)(B >> 16);
    is[4] = (int)(C & 0xFFFFu); is[6] = (int)(C >> 16);
    is[5] = (int)(D & 0xFFFFu); is[7] = (int)(D >> 16);
    float inv = 1.0f / (float)cnt;
    float4 b0 = ((const float4*)bias)[c * 2];
    float4 b1v = ((const float4*)bias)[c * 2 + 1];
    float r[8];
#pragma unroll
    for (int j = 0; j < 8; j++) {
        float s = __int_as_float(colmax2[c * 8 + j]) * (1.0f / 127.0f) * inv;
        r[j] = (float)(is[j] - b128) * s;
    }
    out[(long)node * 16 + c * 2] =
        make_float4(r[0] + b0.x, r[1] + b0.y, r[2] + b0.z, r[3] + b0.w);
    out[(long)node * 16 + c * 2 + 1] =
        make_float4(r[4] + b1v.x, r[5] + b1v.y, r[6] + b1v.z, r[7] + b1v.w);
}

extern "C" void kernel_launch(void* const* d_in, const int* in_sizes, int n_in,
                              void* d_out, int out_size, void* d_ws, size_t ws_size,
                              hipStream_t stream) {
    const float* feat = (const float*)d_in[0];
    const float* W1   = (const float*)d_in[1];
    const float* b1   = (const float*)d_in[2];
    const float* W2   = (const float*)d_in[3];
    const float* b2   = (const float*)d_in[4];
    const int*   src  = (const int*)d_in[5];
    const int*   dst  = (const int*)d_in[6];
    float* out = (float*)d_out;

    // Workspace layout:
    //   bcur    i32[782]        @ 0x0000000
    //   colmax1 i32[128]        @ 0x0001000
    //   colmax2 i32[64]         @ 0x0001400
    //   begs    i32[100000]     @ 0x0002000
    //   ends    i32[100000]     @ 0x0064000
    //   ebuf    i32[NB*CAP]     @ 0x00C8000  (8.0 MB)
    //   csr4    i32[NB*CAP]     @ 0x0900000  (8.0 MB)
    //   z1f/h1  f16[12.8M]      @ 0x1100000  (25.6 MB; h1 reuses z1f)
    //   z1q     u8 [12.8M]      @ 0x2A00000  (12.8 MB)
    //   z2f     f16[6.4M]       @ 0x3700000  (12.8 MB)
    //   z2q     u8 [6.4M]       @ 0x4400000  (6.4 MB)
    //   W1t     f16[16384]      @ 0x4B00000
    //   W2t     f16[8192]       @ 0x4B10000
    char* ws = (char*)d_ws;
    int* bcur    = (int*)(ws + 0x0000000);
    int* colmax1 = (int*)(ws + 0x0001000);
    int* colmax2 = (int*)(ws + 0x0001400);
    int* begs    = (int*)(ws + 0x0002000);
    int* ends    = (int*)(ws + 0x0064000);
    int* ebuf    = (int*)(ws + 0x00C8000);
    int* csr4    = (int*)(ws + 0x0900000);
    f16* z1f     = (f16*)(ws + 0x1100000);
    f16* h1      = (f16*)(ws + 0x1100000);  // reuses z1f (dead after quant)
    unsigned char* z1q = (unsigned char*)(ws + 0x2A00000);
    f16* z2f     = (f16*)(ws + 0x3700000);
    unsigned char* z2q = (unsigned char*)(ws + 0x4400000);
    f16* W1t     = (f16*)(ws + 0x4B00000);
    f16* W2t     = (f16*)(ws + 0x4B10000);

    // 1. init cursors + weight prep + zero column maxes
    init_k<<<100, 256, 0, stream>>>(bcur, W1, W1t, W2, W2t, colmax1, colmax2);

    // 2. edge scatter + layer-1 GEMM (f16 z1 + column maxes)
    scatter_gemm1<<<EBLOCKS + GEMM_BLOCKS, 256, 0, stream>>>(src, dst, bcur, ebuf,
                                                             feat, W1t, z1f,
                                                             colmax1);

    // 3. CSR fill (csr4) + z1 quantize (fused launch, independent block sets)
    fill_quant<<<NB + QBLOCKS, 256, 0, stream>>>(ebuf, bcur, begs, ends, csr4,
                                                 z1f, colmax1, z1q);

    // 4. layer-1 gather (integer accum) -> h1
    gather128_h1<<<NNODES / 16, 256, 0, stream>>>(z1q, csr4, begs, ends,
                                                  colmax1, b1, h1);

    // 5. layer-2 projection -> z2f + column maxes
    gemm2_k<<<GEMM_BLOCKS, 256, 0, stream>>>(h1, W2t, z2f, colmax2);

    // 6. z2 quantize
    quant_z2<<<3125, 256, 0, stream>>>(z2f, colmax2, z2q);

    // 7. layer-2 gather (integer accum) -> output
    gather64<<<3125, 256, 0, stream>>>(z2q, csr4, begs, ends, colmax2, b2,
                                       (float4*)out);
}

// Round 12
// 258.964 us; speedup vs baseline: 1.0454x; 1.0454x over previous
//
#include <hip/hip_runtime.h>

#define NNODES 100000
#define NEDGES 1600000
#define BSHIFT 7
#define NB 782            // buckets of 128 nodes: bucket = dst >> 7
#define CAP 2560          // padded per-bucket capacity (mean 2048, +11 sigma)
#define EBLOCKS 391       // edge-scatter blocks (4096 edges each)
#define GEMM_BLOCKS 1563  // (NNODES + 63) / 64

typedef _Float16 f16;
typedef _Float16 v8h __attribute__((ext_vector_type(8)));
typedef float v4f __attribute__((ext_vector_type(4)));

// Single-instruction byte->float decode (v_cvt_f32_ubyteN), with safe fallback.
#if __has_builtin(__builtin_amdgcn_cvt_f32_ubyte0)
#define CVTB0(u) __builtin_amdgcn_cvt_f32_ubyte0(u)
#define CVTB1(u) __builtin_amdgcn_cvt_f32_ubyte1(u)
#define CVTB2(u) __builtin_amdgcn_cvt_f32_ubyte2(u)
#define CVTB3(u) __builtin_amdgcn_cvt_f32_ubyte3(u)
#else
#define CVTB0(u) ((float)((u) & 0xFFu))
#define CVTB1(u) ((float)(((u) >> 8) & 0xFFu))
#define CVTB2(u) ((float)(((u) >> 16) & 0xFFu))
#define CVTB3(u) ((float)((u) >> 24))
#endif

// decode-accumulate 8 bytes (uint2): a[j] += s * byte_j
__device__ inline void acc8(float s, uint2 u, float* a) {
    a[0] = fmaf(s, CVTB0(u.x), a[0]);
    a[1] = fmaf(s, CVTB1(u.x), a[1]);
    a[2] = fmaf(s, CVTB2(u.x), a[2]);
    a[3] = fmaf(s, CVTB3(u.x), a[3]);
    a[4] = fmaf(s, CVTB0(u.y), a[4]);
    a[5] = fmaf(s, CVTB1(u.y), a[5]);
    a[6] = fmaf(s, CVTB2(u.y), a[6]);
    a[7] = fmaf(s, CVTB3(u.y), a[7]);
}

// ---------------------------------------------------------------------------
// Init: bucket cursors (bcur[b] = b*CAP) + weight transpose/convert to f16.
// ---------------------------------------------------------------------------
__global__ __launch_bounds__(256) void init_k(int* __restrict__ bcur,
                                              const float* __restrict__ W1,
                                              f16* __restrict__ W1t,
                                              const float* __restrict__ W2,
                                              f16* __restrict__ W2t) {
    int t = blockIdx.x * 256 + threadIdx.x;
    if (t < NB) bcur[t] = t * CAP;
    int u = t - 1024;
    if (u >= 0) {
        if (u < 128 * 128) {
            int k = u >> 7, n = u & 127;
            W1t[n * 128 + k] = (f16)W1[k * 128 + n];
        } else if (u < 128 * 128 + 128 * 64) {
            int v = u - 128 * 128;
            int k = v >> 6, n = v & 63;
            W2t[n * 128 + k] = (f16)W2[k * 64 + n];
        }
    }
}

// ---------------------------------------------------------------------------
// Fused: edge scatter into bucket-padded ebuf (blocks 0..EBLOCKS-1) +
// layer-1 MFMA GEMM (remaining blocks). z1 stored as per-row-scaled int8
// (biased uint8, 128 B rows) + sc1[node] = rowmax/127.
// ROUND-12 CHANGE: the GEMM branch reads W1t B-fragments DIRECTLY from
// global (L2-resident 32 KB, ~50 MB of L2 hits chip-wide) instead of LDS
// staging. Static LDS drops 34.8 KB -> 7.2 KB (scatter histogram only),
// lifting the 4-blocks/CU residency cap that held occupancy at 26%.
// ebuf entry packed 4B: src | (dst&127)<<24  (src < 2^17).
// ---------------------------------------------------------------------------
__global__ __launch_bounds__(256) void scatter_gemm1(
    const int* __restrict__ src, const int* __restrict__ dst,
    int* __restrict__ bcur, int* __restrict__ ebuf,
    const float* __restrict__ feat, const f16* __restrict__ W1t,
    unsigned char* __restrict__ z1, float* __restrict__ sc1) {
    __shared__ int hh[1024 + NB];  // h = hh[0..NB), base_s = hh[1024..1024+NB)
    int tid = threadIdx.x;

    if (blockIdx.x < EBLOCKS) {
        int* h = hh;
        int* base_s = hh + 1024;
        for (int i = tid; i < NB; i += 256) h[i] = 0;
        __syncthreads();
        int base = blockIdx.x * 4096;
        int d[16], sv[16];
        for (int k = 0; k < 16; k++) {
            int e = base + k * 256 + tid;
            if (e < NEDGES) {
                d[k] = dst[e];
                sv[k] = src[e];
                atomicAdd(&h[d[k] >> BSHIFT], 1);
            } else {
                d[k] = -1;
            }
        }
        __syncthreads();
        for (int i = tid; i < NB; i += 256) {
            int c = h[i];
            if (c) base_s[i] = atomicAdd(&bcur[i], c);
            h[i] = 0;
        }
        __syncthreads();
        for (int k = 0; k < 16; k++) {
            if (d[k] >= 0) {
                int b = d[k] >> BSHIFT;
                int slot = atomicAdd(&h[b], 1);
                ebuf[base_s[b] + slot] = sv[k] | ((d[k] & 127) << 24);
            }
        }
        return;
    }

    // ---- GEMM-1 branch: z1 = int8(f16(feat) @ W1t^T), per-row scale.
    //      No LDS, no barrier: early-return is safe.
    int wave = tid >> 6, lane = tid & 63, quad = lane >> 4, l16 = lane & 15;
    int m0 = (blockIdx.x - EBLOCKS) * 64 + wave * 16;
    if (m0 >= NNODES) return;  // NNODES % 16 == 0

    v8h a[4];
    const float* arow = feat + (long)(m0 + l16) * 128 + quad * 8;
#pragma unroll
    for (int kb = 0; kb < 4; kb++) {
        float4 f0 = *(const float4*)(arow + kb * 32);
        float4 f1 = *(const float4*)(arow + kb * 32 + 4);
        v8h t = {(f16)f0.x, (f16)f0.y, (f16)f0.z, (f16)f0.w,
                 (f16)f1.x, (f16)f1.y, (f16)f1.z, (f16)f1.w};
        a[kb] = t;
    }

    v4f acc[8];
#pragma unroll
    for (int nt = 0; nt < 8; nt++) {
        v4f c4 = {0.f, 0.f, 0.f, 0.f};
        const f16* brow = W1t + (nt * 16 + l16) * 128 + quad * 8;
#pragma unroll
        for (int kb = 0; kb < 4; kb++) {
            v8h b = *(const v8h*)(brow + kb * 32);
            c4 = __builtin_amdgcn_mfma_f32_16x16x32_f16(a[kb], b, c4, 0, 0, 0);
        }
        acc[nt] = c4;
    }

    // per-row (quad,r) max over 8 nt (lane) x 16 l16 lanes, then int8 encode
#pragma unroll
    for (int r = 0; r < 4; r++) {
        float m = 0.f;
#pragma unroll
        for (int nt = 0; nt < 8; nt++) m = fmaxf(m, fabsf(acc[nt][r]));
        m = fmaxf(m, __shfl_xor(m, 1));
        m = fmaxf(m, __shfl_xor(m, 2));
        m = fmaxf(m, __shfl_xor(m, 4));
        m = fmaxf(m, __shfl_xor(m, 8));
        int row = m0 + quad * 4 + r;
        float rs = (m > 0.f) ? 127.f / m : 0.f;
        if (l16 == 0) sc1[row] = (m > 0.f) ? m / 127.f : 0.f;
#pragma unroll
        for (int nt = 0; nt < 8; nt++) {
            int qv = (int)rintf(acc[nt][r] * rs) + 128;
            z1[(long)row * 128 + nt * 16 + l16] = (unsigned char)qv;
        }
    }
}

// ---------------------------------------------------------------------------
// Per-bucket CSR fill (padded layout). Emits csr8[pos] = {src, f32 sc1[src]}.
// gather128_h1 uses both fields; gather64 uses .x only (its scales are sc2,
// loaded per-edge there -- sc1 packed here is layer-1-only, round-7 lesson).
// ---------------------------------------------------------------------------
__global__ __launch_bounds__(256) void fill_bucket(const int* __restrict__ ebuf,
                                                   const int* __restrict__ bcur,
                                                   const float* __restrict__ sc1,
                                                   int* __restrict__ begs,
                                                   int* __restrict__ ends,
                                                   int2* __restrict__ csr8) {
    __shared__ int lc[128];
    __shared__ int ls[256];
    int b = blockIdx.x;
    int tid = threadIdx.x;
    if (tid < 128) lc[tid] = 0;
    __syncthreads();
    int ebeg = b * CAP;
    int eend = bcur[b];  // = b*CAP + bucket count
    for (int e = ebeg + tid; e < eend; e += 256)
        atomicAdd(&lc[((unsigned)ebuf[e]) >> 24], 1);
    __syncthreads();
    int cnt = (tid < 128) ? lc[tid] : 0;
    ls[tid] = cnt;
    __syncthreads();
    for (int off = 1; off < 256; off <<= 1) {
        int t = (tid >= off) ? ls[tid - off] : 0;
        __syncthreads();
        ls[tid] += t;
        __syncthreads();
    }
    int excl = ls[tid] - cnt;
    int node = (b << BSHIFT) + tid;
    if (tid < 128 && node < NNODES) {
        begs[node] = ebeg + excl;
        ends[node] = ebeg + excl + cnt;
    }
    if (tid < 128) { ls[tid] = excl; lc[tid] = 0; }
    __syncthreads();
    for (int e = ebeg + tid; e < eend; e += 256) {
        int p = ebuf[e];
        int dloc = ((unsigned)p) >> 24;
        int s = p & 0xFFFFFF;
        int slot = atomicAdd(&lc[dloc], 1);
        csr8[ebeg + ls[dloc] + slot] = make_int2(s, __float_as_int(sc1[s]));
    }
}

// ---------------------------------------------------------------------------
// Layer-1 gather -> h1 (f16), BARRIER-FREE + LDS-FREE. 256-thread blocks =
// 16 independent 16-lane subgroups, one node each. Waves retire as they
// finish; 8 blocks/CU keep the CU fed past stragglers. csr8 {src,scale}
// broadcast load; decode = v_cvt_f32_ubyteN + bias identity.
// ---------------------------------------------------------------------------
__global__ __launch_bounds__(256, 8) void gather128_h1(
    const unsigned char* __restrict__ z,  // z1, 128 B int8 rows
    const float* __restrict__ sc,         // sc1[NNODES] (self term)
    const int2* __restrict__ csr8,        // {src, f32 sc1-scale}
    const int* __restrict__ begs, const int* __restrict__ ends,
    const float* __restrict__ b1,     // [128]
    f16* __restrict__ h1)             // [NNODES,128] f16
{
    int tid = threadIdx.x;
    int c = tid & 15;                         // channel block: c*8 .. c*8+7
    int node = blockIdx.x * 16 + (tid >> 4);  // 6250*16 == NNODES exactly

    int beg = begs[node];
    int end = ends[node];

    unsigned coff = (unsigned)c << 3;   // byte offset of this lane's 8B chunk

    float a[8];
#pragma unroll
    for (int j = 0; j < 8; j++) a[j] = 0.f;
    float ssum = 0.f;

    // self row
    {
        float s = sc[node];
        uint2 u = *(const uint2*)(z + (((unsigned)node) << 7) + coff);
        ssum += s;
        acc8(s, u, a);
    }

    int e = beg;
    while (__any(e < end)) {
        int2 q0 = {0, 0}, q1 = {0, 0}, q2 = {0, 0}, q3 = {0, 0};
        int2 q4 = {0, 0}, q5 = {0, 0}, q6 = {0, 0}, q7 = {0, 0};
        if (e     < end) q0 = csr8[e];
        if (e + 1 < end) q1 = csr8[e + 1];
        if (e + 2 < end) q2 = csr8[e + 2];
        if (e + 3 < end) q3 = csr8[e + 3];
        if (e + 4 < end) q4 = csr8[e + 4];
        if (e + 5 < end) q5 = csr8[e + 5];
        if (e + 6 < end) q6 = csr8[e + 6];
        if (e + 7 < end) q7 = csr8[e + 7];
        uint2 u0 = make_uint2(0, 0), u1 = make_uint2(0, 0);
        uint2 u2 = make_uint2(0, 0), u3 = make_uint2(0, 0);
        uint2 u4 = make_uint2(0, 0), u5 = make_uint2(0, 0);
        uint2 u6 = make_uint2(0, 0), u7 = make_uint2(0, 0);
        if (e     < end) u0 = *(const uint2*)(z + (((unsigned)q0.x) << 7) + coff);
        if (e + 1 < end) u1 = *(const uint2*)(z + (((unsigned)q1.x) << 7) + coff);
        if (e + 2 < end) u2 = *(const uint2*)(z + (((unsigned)q2.x) << 7) + coff);
        if (e + 3 < end) u3 = *(const uint2*)(z + (((unsigned)q3.x) << 7) + coff);
        if (e + 4 < end) u4 = *(const uint2*)(z + (((unsigned)q4.x) << 7) + coff);
        if (e + 5 < end) u5 = *(const uint2*)(z + (((unsigned)q5.x) << 7) + coff);
        if (e + 6 < end) u6 = *(const uint2*)(z + (((unsigned)q6.x) << 7) + coff);
        if (e + 7 < end) u7 = *(const uint2*)(z + (((unsigned)q7.x) << 7) + coff);
        float s0 = __int_as_float(q0.y), s1 = __int_as_float(q1.y);
        float s2 = __int_as_float(q2.y), s3 = __int_as_float(q3.y);
        float s4 = __int_as_float(q4.y), s5 = __int_as_float(q5.y);
        float s6 = __int_as_float(q6.y), s7 = __int_as_float(q7.y);
        ssum += ((s0 + s1) + (s2 + s3)) + ((s4 + s5) + (s6 + s7));
        acc8(s0, u0, a); acc8(s1, u1, a); acc8(s2, u2, a); acc8(s3, u3, a);
        acc8(s4, u4, a); acc8(s5, u5, a); acc8(s6, u6, a); acc8(s7, u7, a);
        e += 8;
    }

    // normalize + bias + relu -> h1 row (coalesced 256B per subgroup)
    {
        float base = 128.f * ssum;
        float inv = 1.0f / (float)(end - beg + 1);
        float4 bb0 = ((const float4*)b1)[c * 2];
        float4 bb1 = ((const float4*)b1)[c * 2 + 1];
        v8h o = {(f16)fmaxf((a[0] - base) * inv + bb0.x, 0.f),
                 (f16)fmaxf((a[1] - base) * inv + bb0.y, 0.f),
                 (f16)fmaxf((a[2] - base) * inv + bb0.z, 0.f),
                 (f16)fmaxf((a[3] - base) * inv + bb0.w, 0.f),
                 (f16)fmaxf((a[4] - base) * inv + bb1.x, 0.f),
                 (f16)fmaxf((a[5] - base) * inv + bb1.y, 0.f),
                 (f16)fmaxf((a[6] - base) * inv + bb1.z, 0.f),
                 (f16)fmaxf((a[7] - base) * inv + bb1.w, 0.f)};
        *(v8h*)&h1[(long)node * 128 + c * 8] = o;
    }
}

// ---------------------------------------------------------------------------
// Standalone layer-2 projection: z2 = int8(h1 @ W2t^T) + sc2. 4 waves x 16
// rows, W2t in LDS (17.4 KB -> not occupancy-limiting at 256 threads),
// f16 A loads from h1, 4 n-tiles, shfl rowmax encode.
// ---------------------------------------------------------------------------
__global__ __launch_bounds__(256) void gemm2_k(
    const f16* __restrict__ h1,       // [NNODES,128]
    const f16* __restrict__ W2t,      // [64,128]
    unsigned char* __restrict__ z2,   // [NNODES,64] int8
    float* __restrict__ sc2)          // sc2[NNODES]
{
    constexpr int PITCH = 136;
    __shared__ f16 wlds[64 * PITCH];  // 17408 B
    int tid = threadIdx.x;
    for (int c = tid; c < 64 * 16; c += 256) {
        int n = c >> 4;
        int kc = c & 15;
        *(v8h*)&wlds[n * PITCH + kc * 8] = *(const v8h*)&W2t[n * 128 + kc * 8];
    }
    __syncthreads();

    int wave = tid >> 6, lane = tid & 63, quad = lane >> 4, l16 = lane & 15;
    int m0 = blockIdx.x * 64 + wave * 16;
    if (m0 >= NNODES) return;  // NNODES % 16 == 0

    v8h a[4];
    const f16* arow = h1 + (long)(m0 + l16) * 128 + quad * 8;
#pragma unroll
    for (int kb = 0; kb < 4; kb++) a[kb] = *(const v8h*)(arow + kb * 32);

    v4f acc[4];
#pragma unroll
    for (int nt = 0; nt < 4; nt++) {
        v4f c4 = {0.f, 0.f, 0.f, 0.f};
        const f16* brow = &wlds[(nt * 16 + l16) * PITCH + quad * 8];
#pragma unroll
        for (int kb = 0; kb < 4; kb++) {
            v8h b = *(const v8h*)(brow + kb * 32);
            c4 = __builtin_amdgcn_mfma_f32_16x16x32_f16(a[kb], b, c4, 0, 0, 0);
        }
        acc[nt] = c4;
    }

#pragma unroll
    for (int r = 0; r < 4; r++) {
        float m = 0.f;
#pragma unroll
        for (int nt = 0; nt < 4; nt++) m = fmaxf(m, fabsf(acc[nt][r]));
        m = fmaxf(m, __shfl_xor(m, 1));
        m = fmaxf(m, __shfl_xor(m, 2));
        m = fmaxf(m, __shfl_xor(m, 4));
        m = fmaxf(m, __shfl_xor(m, 8));
        int row = m0 + quad * 4 + r;
        float rs = (m > 0.f) ? 127.f / m : 0.f;
        if (l16 == 0) sc2[row] = (m > 0.f) ? m / 127.f : 0.f;
#pragma unroll
        for (int nt = 0; nt < 4; nt++) {
            int qv = (int)rintf(acc[nt][r] * rs) + 128;
            z2[(long)row * 64 + nt * 16 + l16] = (unsigned char)qv;
        }
    }
}

// ---------------------------------------------------------------------------
// Layer-2 gather+normalize, SUBGROUP-PER-NODE, int8 rows: wave = 8x 8-lane
// subgroups, one node per subgroup (8 lanes x 8B = full 64B int8 z2 row =
// ONE cache line per gather). csr8.x index + per-edge sc2 load (sc2 400KB,
// L2-resident; csr8.y is sc1 -- wrong layer here, must NOT be used).
// ---------------------------------------------------------------------------
__global__ __launch_bounds__(256, 8) void gather64(
    const unsigned char* __restrict__ z, const float* __restrict__ sc,
    const int2* __restrict__ csr8,
    const int* __restrict__ begs, const int* __restrict__ ends,
    const float* __restrict__ bias, float4* __restrict__ out) {
    int tid = threadIdx.x;
    int lane = tid & 63;
    int c = lane & 7;                         // channel block: c*8..c*8+7
    int node = blockIdx.x * 32 + (tid >> 3);  // 3125*32 == NNODES exactly

    int beg = begs[node];
    int end = ends[node];

    unsigned coff = (unsigned)c << 3;

    float a[8];
#pragma unroll
    for (int j = 0; j < 8; j++) a[j] = 0.f;
    float ssum = 0.f;

    {
        float s = sc[node];
        uint2 u = *(const uint2*)(z + (((unsigned)node) << 6) + coff);
        ssum += s;
        acc8(s, u, a);
    }

    int e = beg;
    while (__any(e < end)) {
        float s0 = 0.f, s1 = 0.f, s2 = 0.f, s3 = 0.f;
        float s4 = 0.f, s5 = 0.f, s6 = 0.f, s7 = 0.f;
        uint2 u0 = make_uint2(0, 0), u1 = make_uint2(0, 0);
        uint2 u2 = make_uint2(0, 0), u3 = make_uint2(0, 0);
        uint2 u4 = make_uint2(0, 0), u5 = make_uint2(0, 0);
        uint2 u6 = make_uint2(0, 0), u7 = make_uint2(0, 0);
        if (e     < end) { int i = csr8[e    ].x; s0 = sc[i]; u0 = *(const uint2*)(z + (((unsigned)i) << 6) + coff); }
        if (e + 1 < end) { int i = csr8[e + 1].x; s1 = sc[i]; u1 = *(const uint2*)(z + (((unsigned)i) << 6) + coff); }
        if (e + 2 < end) { int i = csr8[e + 2].x; s2 = sc[i]; u2 = *(const uint2*)(z + (((unsigned)i) << 6) + coff); }
        if (e + 3 < end) { int i = csr8[e + 3].x; s3 = sc[i]; u3 = *(const uint2*)(z + (((unsigned)i) << 6) + coff); }
        if (e + 4 < end) { int i = csr8[e + 4].x; s4 = sc[i]; u4 = *(const uint2*)(z + (((unsigned)i) << 6) + coff); }
        if (e + 5 < end) { int i = csr8[e + 5].x; s5 = sc[i]; u5 = *(const uint2*)(z + (((unsigned)i) << 6) + coff); }
        if (e + 6 < end) { int i = csr8[e + 6].x; s6 = sc[i]; u6 = *(const uint2*)(z + (((unsigned)i) << 6) + coff); }
        if (e + 7 < end) { int i = csr8[e + 7].x; s7 = sc[i]; u7 = *(const uint2*)(z + (((unsigned)i) << 6) + coff); }
        ssum += ((s0 + s1) + (s2 + s3)) + ((s4 + s5) + (s6 + s7));
        acc8(s0, u0, a); acc8(s1, u1, a); acc8(s2, u2, a); acc8(s3, u3, a);
        acc8(s4, u4, a); acc8(s5, u5, a); acc8(s6, u6, a); acc8(s7, u7, a);
        e += 8;
    }

    {
        float base = 128.f * ssum;
        float inv = 1.0f / (float)(end - beg + 1);
        float4 b0 = ((const float4*)bias)[c * 2];
        float4 b1v = ((const float4*)bias)[c * 2 + 1];
        out[(long)node * 16 + c * 2] =
            make_float4((a[0] - base) * inv + b0.x, (a[1] - base) * inv + b0.y,
                        (a[2] - base) * inv + b0.z, (a[3] - base) * inv + b0.w);
        out[(long)node * 16 + c * 2 + 1] =
            make_float4((a[4] - base) * inv + b1v.x, (a[5] - base) * inv + b1v.y,
                        (a[6] - base) * inv + b1v.z, (a[7] - base) * inv + b1v.w);
    }
}

extern "C" void kernel_launch(void* const* d_in, const int* in_sizes, int n_in,
                              void* d_out, int out_size, void* d_ws, size_t ws_size,
                              hipStream_t stream) {
    const float* feat = (const float*)d_in[0];
    const float* W1   = (const float*)d_in[1];
    const float* b1   = (const float*)d_in[2];
    const float* W2   = (const float*)d_in[3];
    const float* b2   = (const float*)d_in[4];
    const int*   src  = (const int*)d_in[5];
    const int*   dst  = (const int*)d_in[6];
    float* out = (float*)d_out;

    // Workspace layout:
    //   bcur i32[782]            @ 0x0000000
    //   begs i32[100000]         @ 0x0001000
    //   ends i32[100000]         @ 0x0063000
    //   ebuf i32[NB*CAP]         @ 0x00C5000  (8.0 MB)
    //   csr8 int2[NB*CAP]        @ 0x0900000  (16.0 MB)
    //   z1   u8 [12.8M]          @ 0x1900000
    //   sc1  f32[100000]         @ 0x2600000
    //   h1   f16[12.8M]          @ 0x2700000  (25.6 MB)
    //   z2   u8 [6.4M]           @ 0x4100000
    //   sc2  f32[100000]         @ 0x4800000
    //   W1t  f16[16384]          @ 0x4900000
    //   W2t  f16[8192]           @ 0x4910000
    char* ws = (char*)d_ws;
    int* bcur = (int*)(ws + 0x0000000);
    int* begs = (int*)(ws + 0x0001000);
    int* ends = (int*)(ws + 0x0063000);
    int* ebuf = (int*)(ws + 0x00C5000);
    int2* csr8 = (int2*)(ws + 0x0900000);
    unsigned char* z1 = (unsigned char*)(ws + 0x1900000);
    float* sc1 = (float*)(ws + 0x2600000);
    f16* h1   = (f16*)(ws + 0x2700000);
    unsigned char* z2 = (unsigned char*)(ws + 0x4100000);
    float* sc2 = (float*)(ws + 0x4800000);
    f16* W1t  = (f16*)(ws + 0x4900000);
    f16* W2t  = (f16*)(ws + 0x4910000);

    // 1. init cursors + weight prep (no memsets needed anywhere)
    init_k<<<100, 256, 0, stream>>>(bcur, W1, W1t, W2, W2t);

    // 2. edge scatter into padded buckets + layer-1 GEMM (fused, LDS-light)
    scatter_gemm1<<<EBLOCKS + GEMM_BLOCKS, 256, 0, stream>>>(src, dst, bcur, ebuf,
                                                             feat, W1t, z1, sc1);

    // 3. per-bucket CSR fill ({src,sc1} csr8) + per-node beg/end
    fill_bucket<<<NB, 256, 0, stream>>>(ebuf, bcur, sc1, begs, ends, csr8);

    // 4. layer-1 gather (+bias+relu) -> h1, barrier-free small blocks
    gather128_h1<<<NNODES / 16, 256, 0, stream>>>(z1, sc1, csr8, begs, ends,
                                                  b1, h1);

    // 5. layer-2 projection: z2 = int8(h1 @ W2t^T) + sc2
    gemm2_k<<<GEMM_BLOCKS, 256, 0, stream>>>(h1, W2t, z2, sc2);

    // 6. layer-2 gather (+bias) -> output; 32 nodes/block, 3125*32 = 100000
    gather64<<<3125, 256, 0, stream>>>(z2, sc2, csr8, begs, ends, b2,
                                       (float4*)out);
}

// Round 13
// 252.101 us; speedup vs baseline: 1.0739x; 1.0272x over previous
//
#include <hip/hip_runtime.h>

#define NNODES 100000
#define NEDGES 1600000
#define BSHIFT 7
#define NB 782            // buckets of 128 nodes: bucket = dst >> 7
#define CAP 2560          // padded per-bucket capacity (mean 2048, +11 sigma)
#define EBLOCKS 391       // edge-scatter blocks (4096 edges each)
#define GEMM_BLOCKS 1563  // (NNODES + 63) / 64

typedef _Float16 f16;
typedef _Float16 v8h __attribute__((ext_vector_type(8)));
typedef float v4f __attribute__((ext_vector_type(4)));

// Single-instruction byte->float decode (v_cvt_f32_ubyteN), with safe fallback.
#if __has_builtin(__builtin_amdgcn_cvt_f32_ubyte0)
#define CVTB0(u) __builtin_amdgcn_cvt_f32_ubyte0(u)
#define CVTB1(u) __builtin_amdgcn_cvt_f32_ubyte1(u)
#define CVTB2(u) __builtin_amdgcn_cvt_f32_ubyte2(u)
#define CVTB3(u) __builtin_amdgcn_cvt_f32_ubyte3(u)
#else
#define CVTB0(u) ((float)((u) & 0xFFu))
#define CVTB1(u) ((float)(((u) >> 8) & 0xFFu))
#define CVTB2(u) ((float)(((u) >> 16) & 0xFFu))
#define CVTB3(u) ((float)((u) >> 24))
#endif

// decode-accumulate 8 bytes (uint2): a[j] += s * byte_j
__device__ inline void acc8(float s, uint2 u, float* a) {
    a[0] = fmaf(s, CVTB0(u.x), a[0]);
    a[1] = fmaf(s, CVTB1(u.x), a[1]);
    a[2] = fmaf(s, CVTB2(u.x), a[2]);
    a[3] = fmaf(s, CVTB3(u.x), a[3]);
    a[4] = fmaf(s, CVTB0(u.y), a[4]);
    a[5] = fmaf(s, CVTB1(u.y), a[5]);
    a[6] = fmaf(s, CVTB2(u.y), a[6]);
    a[7] = fmaf(s, CVTB3(u.y), a[7]);
}

// ---------------------------------------------------------------------------
// Init: bucket cursors (bcur[b] = b*CAP) + weight transpose/convert to f16.
// ---------------------------------------------------------------------------
__global__ __launch_bounds__(256) void init_k(int* __restrict__ bcur,
                                              const float* __restrict__ W1,
                                              f16* __restrict__ W1t,
                                              const float* __restrict__ W2,
                                              f16* __restrict__ W2t) {
    int t = blockIdx.x * 256 + threadIdx.x;
    if (t < NB) bcur[t] = t * CAP;
    int u = t - 1024;
    if (u >= 0) {
        if (u < 128 * 128) {
            int k = u >> 7, n = u & 127;
            W1t[n * 128 + k] = (f16)W1[k * 128 + n];
        } else if (u < 128 * 128 + 128 * 64) {
            int v = u - 128 * 128;
            int k = v >> 6, n = v & 63;
            W2t[n * 128 + k] = (f16)W2[k * 64 + n];
        }
    }
}

// ---------------------------------------------------------------------------
// Fused: edge scatter into bucket-padded ebuf (blocks 0..EBLOCKS-1) +
// layer-1 MFMA GEMM (remaining blocks). z1 stored as per-row-scaled int8
// (biased uint8, 128 B rows) + sc1[node] = rowmax/127.
// LDS W1t staging RESTORED (round-12 A/B: LDS=48.5us vs global=53.9us --
// occupancy was never LDS-capped; global W1t reads just add load latency
// into the MFMA chain).
// ebuf entry packed 4B: src | (dst&127)<<24  (src < 2^17).
// ---------------------------------------------------------------------------
__global__ __launch_bounds__(256) void scatter_gemm1(
    const int* __restrict__ src, const int* __restrict__ dst,
    int* __restrict__ bcur, int* __restrict__ ebuf,
    const float* __restrict__ feat, const f16* __restrict__ W1t,
    unsigned char* __restrict__ z1, float* __restrict__ sc1) {
    constexpr int PITCH = 136;
    __shared__ __align__(16) char smem[128 * PITCH * 2];  // 34816 B
    int tid = threadIdx.x;

    if (blockIdx.x < EBLOCKS) {
        int* h = (int*)smem;
        int* base_s = ((int*)smem) + 1024;
        for (int i = tid; i < NB; i += 256) h[i] = 0;
        __syncthreads();
        int base = blockIdx.x * 4096;
        int d[16], sv[16];
        for (int k = 0; k < 16; k++) {
            int e = base + k * 256 + tid;
            if (e < NEDGES) {
                d[k] = dst[e];
                sv[k] = src[e];
                atomicAdd(&h[d[k] >> BSHIFT], 1);
            } else {
                d[k] = -1;
            }
        }
        __syncthreads();
        for (int i = tid; i < NB; i += 256) {
            int c = h[i];
            if (c) base_s[i] = atomicAdd(&bcur[i], c);
            h[i] = 0;
        }
        __syncthreads();
        for (int k = 0; k < 16; k++) {
            if (d[k] >= 0) {
                int b = d[k] >> BSHIFT;
                int slot = atomicAdd(&h[b], 1);
                ebuf[base_s[b] + slot] = sv[k] | ((d[k] & 127) << 24);
            }
        }
        return;
    }

    // ---- GEMM-1 branch: z1 = int8(f16(feat) @ W1t^T), per-row scale ----
    f16* wlds = (f16*)smem;
    for (int c = tid; c < 128 * 16; c += 256) {
        int n = c >> 4;
        int kc = c & 15;
        *(v8h*)&wlds[n * PITCH + kc * 8] = *(const v8h*)&W1t[n * 128 + kc * 8];
    }
    __syncthreads();

    int wave = tid >> 6, lane = tid & 63, quad = lane >> 4, l16 = lane & 15;
    int m0 = (blockIdx.x - EBLOCKS) * 64 + wave * 16;
    if (m0 >= NNODES) return;  // NNODES % 16 == 0

    v8h a[4];
    const float* arow = feat + (long)(m0 + l16) * 128 + quad * 8;
#pragma unroll
    for (int kb = 0; kb < 4; kb++) {
        float4 f0 = *(const float4*)(arow + kb * 32);
        float4 f1 = *(const float4*)(arow + kb * 32 + 4);
        v8h t = {(f16)f0.x, (f16)f0.y, (f16)f0.z, (f16)f0.w,
                 (f16)f1.x, (f16)f1.y, (f16)f1.z, (f16)f1.w};
        a[kb] = t;
    }

    v4f acc[8];
#pragma unroll
    for (int nt = 0; nt < 8; nt++) {
        v4f c4 = {0.f, 0.f, 0.f, 0.f};
        const f16* brow = &wlds[(nt * 16 + l16) * PITCH + quad * 8];
#pragma unroll
        for (int kb = 0; kb < 4; kb++) {
            v8h b = *(const v8h*)(brow + kb * 32);
            c4 = __builtin_amdgcn_mfma_f32_16x16x32_f16(a[kb], b, c4, 0, 0, 0);
        }
        acc[nt] = c4;
    }

    // per-row (quad,r) max over 8 nt (lane) x 16 l16 lanes, then int8 encode
#pragma unroll
    for (int r = 0; r < 4; r++) {
        float m = 0.f;
#pragma unroll
        for (int nt = 0; nt < 8; nt++) m = fmaxf(m, fabsf(acc[nt][r]));
        m = fmaxf(m, __shfl_xor(m, 1));
        m = fmaxf(m, __shfl_xor(m, 2));
        m = fmaxf(m, __shfl_xor(m, 4));
        m = fmaxf(m, __shfl_xor(m, 8));
        int row = m0 + quad * 4 + r;
        float rs = (m > 0.f) ? 127.f / m : 0.f;
        if (l16 == 0) sc1[row] = (m > 0.f) ? m / 127.f : 0.f;
#pragma unroll
        for (int nt = 0; nt < 8; nt++) {
            int qv = (int)rintf(acc[nt][r] * rs) + 128;
            z1[(long)row * 128 + nt * 16 + l16] = (unsigned char)qv;
        }
    }
}

// ---------------------------------------------------------------------------
// Per-bucket CSR fill (padded layout). Emits csr8[pos] = {src, f32 sc1[src]}.
// gather128_h1 uses both fields; gather64 uses .x only (its scales are sc2,
// loaded per-edge there -- sc1 packed here is layer-1-only, round-7 lesson).
// ---------------------------------------------------------------------------
__global__ __launch_bounds__(256) void fill_bucket(const int* __restrict__ ebuf,
                                                   const int* __restrict__ bcur,
                                                   const float* __restrict__ sc1,
                                                   int* __restrict__ begs,
                                                   int* __restrict__ ends,
                                                   int2* __restrict__ csr8) {
    __shared__ int lc[128];
    __shared__ int ls[256];
    int b = blockIdx.x;
    int tid = threadIdx.x;
    if (tid < 128) lc[tid] = 0;
    __syncthreads();
    int ebeg = b * CAP;
    int eend = bcur[b];  // = b*CAP + bucket count
    for (int e = ebeg + tid; e < eend; e += 256)
        atomicAdd(&lc[((unsigned)ebuf[e]) >> 24], 1);
    __syncthreads();
    int cnt = (tid < 128) ? lc[tid] : 0;
    ls[tid] = cnt;
    __syncthreads();
    for (int off = 1; off < 256; off <<= 1) {
        int t = (tid >= off) ? ls[tid - off] : 0;
        __syncthreads();
        ls[tid] += t;
        __syncthreads();
    }
    int excl = ls[tid] - cnt;
    int node = (b << BSHIFT) + tid;
    if (tid < 128 && node < NNODES) {
        begs[node] = ebeg + excl;
        ends[node] = ebeg + excl + cnt;
    }
    if (tid < 128) { ls[tid] = excl; lc[tid] = 0; }
    __syncthreads();
    for (int e = ebeg + tid; e < eend; e += 256) {
        int p = ebuf[e];
        int dloc = ((unsigned)p) >> 24;
        int s = p & 0xFFFFFF;
        int slot = atomicAdd(&lc[dloc], 1);
        csr8[ebeg + ls[dloc] + slot] = make_int2(s, __float_as_int(sc1[s]));
    }
}

// ---------------------------------------------------------------------------
// Layer-1 gather -> h1 (f16), BARRIER-FREE + LDS-FREE. 256-thread blocks =
// 16 independent 16-lane subgroups, one node each. No __syncthreads, no
// epilogue: waves retire as they finish, 8 blocks/CU keep the CU fed past
// stragglers. csr8 {src,scale} broadcast load; v_cvt_f32_ubyteN decode +
// bias identity: sum = SUM s_i*(q_i+128) - 128*SUM s_i (masked edges s=0).
// ---------------------------------------------------------------------------
__global__ __launch_bounds__(256, 8) void gather128_h1(
    const unsigned char* __restrict__ z,  // z1, 128 B int8 rows
    const float* __restrict__ sc,         // sc1[NNODES] (self term)
    const int2* __restrict__ csr8,        // {src, f32 sc1-scale}
    const int* __restrict__ begs, const int* __restrict__ ends,
    const float* __restrict__ b1,     // [128]
    f16* __restrict__ h1)             // [NNODES,128] f16
{
    int tid = threadIdx.x;
    int c = tid & 15;                         // channel block: c*8 .. c*8+7
    int node = blockIdx.x * 16 + (tid >> 4);  // 6250*16 == NNODES exactly

    int beg = begs[node];
    int end = ends[node];

    unsigned coff = (unsigned)c << 3;   // byte offset of this lane's 8B chunk

    float a[8];
#pragma unroll
    for (int j = 0; j < 8; j++) a[j] = 0.f;
    float ssum = 0.f;

    // self row
    {
        float s = sc[node];
        uint2 u = *(const uint2*)(z + (((unsigned)node) << 7) + coff);
        ssum += s;
        acc8(s, u, a);
    }

    int e = beg;
    while (__any(e < end)) {
        int2 q0 = {0, 0}, q1 = {0, 0}, q2 = {0, 0}, q3 = {0, 0};
        int2 q4 = {0, 0}, q5 = {0, 0}, q6 = {0, 0}, q7 = {0, 0};
        if (e     < end) q0 = csr8[e];
        if (e + 1 < end) q1 = csr8[e + 1];
        if (e + 2 < end) q2 = csr8[e + 2];
        if (e + 3 < end) q3 = csr8[e + 3];
        if (e + 4 < end) q4 = csr8[e + 4];
        if (e + 5 < end) q5 = csr8[e + 5];
        if (e + 6 < end) q6 = csr8[e + 6];
        if (e + 7 < end) q7 = csr8[e + 7];
        uint2 u0 = make_uint2(0, 0), u1 = make_uint2(0, 0);
        uint2 u2 = make_uint2(0, 0), u3 = make_uint2(0, 0);
        uint2 u4 = make_uint2(0, 0), u5 = make_uint2(0, 0);
        uint2 u6 = make_uint2(0, 0), u7 = make_uint2(0, 0);
        if (e     < end) u0 = *(const uint2*)(z + (((unsigned)q0.x) << 7) + coff);
        if (e + 1 < end) u1 = *(const uint2*)(z + (((unsigned)q1.x) << 7) + coff);
        if (e + 2 < end) u2 = *(const uint2*)(z + (((unsigned)q2.x) << 7) + coff);
        if (e + 3 < end) u3 = *(const uint2*)(z + (((unsigned)q3.x) << 7) + coff);
        if (e + 4 < end) u4 = *(const uint2*)(z + (((unsigned)q4.x) << 7) + coff);
        if (e + 5 < end) u5 = *(const uint2*)(z + (((unsigned)q5.x) << 7) + coff);
        if (e + 6 < end) u6 = *(const uint2*)(z + (((unsigned)q6.x) << 7) + coff);
        if (e + 7 < end) u7 = *(const uint2*)(z + (((unsigned)q7.x) << 7) + coff);
        float s0 = __int_as_float(q0.y), s1 = __int_as_float(q1.y);
        float s2 = __int_as_float(q2.y), s3 = __int_as_float(q3.y);
        float s4 = __int_as_float(q4.y), s5 = __int_as_float(q5.y);
        float s6 = __int_as_float(q6.y), s7 = __int_as_float(q7.y);
        ssum += ((s0 + s1) + (s2 + s3)) + ((s4 + s5) + (s6 + s7));
        acc8(s0, u0, a); acc8(s1, u1, a); acc8(s2, u2, a); acc8(s3, u3, a);
        acc8(s4, u4, a); acc8(s5, u5, a); acc8(s6, u6, a); acc8(s7, u7, a);
        e += 8;
    }

    // normalize + bias + relu -> h1 row (coalesced 256B per subgroup)
    {
        float base = 128.f * ssum;
        float inv = 1.0f / (float)(end - beg + 1);
        float4 bb0 = ((const float4*)b1)[c * 2];
        float4 bb1 = ((const float4*)b1)[c * 2 + 1];
        v8h o = {(f16)fmaxf((a[0] - base) * inv + bb0.x, 0.f),
                 (f16)fmaxf((a[1] - base) * inv + bb0.y, 0.f),
                 (f16)fmaxf((a[2] - base) * inv + bb0.z, 0.f),
                 (f16)fmaxf((a[3] - base) * inv + bb0.w, 0.f),
                 (f16)fmaxf((a[4] - base) * inv + bb1.x, 0.f),
                 (f16)fmaxf((a[5] - base) * inv + bb1.y, 0.f),
                 (f16)fmaxf((a[6] - base) * inv + bb1.z, 0.f),
                 (f16)fmaxf((a[7] - base) * inv + bb1.w, 0.f)};
        *(v8h*)&h1[(long)node * 128 + c * 8] = o;
    }
}

// ---------------------------------------------------------------------------
// Standalone layer-2 projection: z2 = int8(h1 @ W2t^T) + sc2. 4 waves x 16
// rows, W2t in LDS, f16 A loads from h1, 4 n-tiles, shfl rowmax encode.
// ---------------------------------------------------------------------------
__global__ __launch_bounds__(256) void gemm2_k(
    const f16* __restrict__ h1,       // [NNODES,128]
    const f16* __restrict__ W2t,      // [64,128]
    unsigned char* __restrict__ z2,   // [NNODES,64] int8
    float* __restrict__ sc2)          // sc2[NNODES]
{
    constexpr int PITCH = 136;
    __shared__ f16 wlds[64 * PITCH];  // 17408 B
    int tid = threadIdx.x;
    for (int c = tid; c < 64 * 16; c += 256) {
        int n = c >> 4;
        int kc = c & 15;
        *(v8h*)&wlds[n * PITCH + kc * 8] = *(const v8h*)&W2t[n * 128 + kc * 8];
    }
    __syncthreads();

    int wave = tid >> 6, lane = tid & 63, quad = lane >> 4, l16 = lane & 15;
    int m0 = blockIdx.x * 64 + wave * 16;
    if (m0 >= NNODES) return;  // NNODES % 16 == 0

    v8h a[4];
    const f16* arow = h1 + (long)(m0 + l16) * 128 + quad * 8;
#pragma unroll
    for (int kb = 0; kb < 4; kb++) a[kb] = *(const v8h*)(arow + kb * 32);

    v4f acc[4];
#pragma unroll
    for (int nt = 0; nt < 4; nt++) {
        v4f c4 = {0.f, 0.f, 0.f, 0.f};
        const f16* brow = &wlds[(nt * 16 + l16) * PITCH + quad * 8];
#pragma unroll
        for (int kb = 0; kb < 4; kb++) {
            v8h b = *(const v8h*)(brow + kb * 32);
            c4 = __builtin_amdgcn_mfma_f32_16x16x32_f16(a[kb], b, c4, 0, 0, 0);
        }
        acc[nt] = c4;
    }

#pragma unroll
    for (int r = 0; r < 4; r++) {
        float m = 0.f;
#pragma unroll
        for (int nt = 0; nt < 4; nt++) m = fmaxf(m, fabsf(acc[nt][r]));
        m = fmaxf(m, __shfl_xor(m, 1));
        m = fmaxf(m, __shfl_xor(m, 2));
        m = fmaxf(m, __shfl_xor(m, 4));
        m = fmaxf(m, __shfl_xor(m, 8));
        int row = m0 + quad * 4 + r;
        float rs = (m > 0.f) ? 127.f / m : 0.f;
        if (l16 == 0) sc2[row] = (m > 0.f) ? m / 127.f : 0.f;
#pragma unroll
        for (int nt = 0; nt < 4; nt++) {
            int qv = (int)rintf(acc[nt][r] * rs) + 128;
            z2[(long)row * 64 + nt * 16 + l16] = (unsigned char)qv;
        }
    }
}

// ---------------------------------------------------------------------------
// Layer-2 gather+normalize, SUBGROUP-PER-NODE, int8 rows: wave = 8x 8-lane
// subgroups, one node per subgroup (8 lanes x 8B = full 64B int8 z2 row =
// ONE cache line per gather). csr8.x index + per-edge sc2 load (sc2 400KB,
// L2-resident; csr8.y is sc1 -- wrong layer here, must NOT be used).
// ---------------------------------------------------------------------------
__global__ __launch_bounds__(256, 8) void gather64(
    const unsigned char* __restrict__ z, const float* __restrict__ sc,
    const int2* __restrict__ csr8,
    const int* __restrict__ begs, const int* __restrict__ ends,
    const float* __restrict__ bias, float4* __restrict__ out) {
    int tid = threadIdx.x;
    int lane = tid & 63;
    int c = lane & 7;                         // channel block: c*8..c*8+7
    int node = blockIdx.x * 32 + (tid >> 3);  // 3125*32 == NNODES exactly

    int beg = begs[node];
    int end = ends[node];

    unsigned coff = (unsigned)c << 3;

    float a[8];
#pragma unroll
    for (int j = 0; j < 8; j++) a[j] = 0.f;
    float ssum = 0.f;

    {
        float s = sc[node];
        uint2 u = *(const uint2*)(z + (((unsigned)node) << 6) + coff);
        ssum += s;
        acc8(s, u, a);
    }

    int e = beg;
    while (__any(e < end)) {
        float s0 = 0.f, s1 = 0.f, s2 = 0.f, s3 = 0.f;
        float s4 = 0.f, s5 = 0.f, s6 = 0.f, s7 = 0.f;
        uint2 u0 = make_uint2(0, 0), u1 = make_uint2(0, 0);
        uint2 u2 = make_uint2(0, 0), u3 = make_uint2(0, 0);
        uint2 u4 = make_uint2(0, 0), u5 = make_uint2(0, 0);
        uint2 u6 = make_uint2(0, 0), u7 = make_uint2(0, 0);
        if (e     < end) { int i = csr8[e    ].x; s0 = sc[i]; u0 = *(const uint2*)(z + (((unsigned)i) << 6) + coff); }
        if (e + 1 < end) { int i = csr8[e + 1].x; s1 = sc[i]; u1 = *(const uint2*)(z + (((unsigned)i) << 6) + coff); }
        if (e + 2 < end) { int i = csr8[e + 2].x; s2 = sc[i]; u2 = *(const uint2*)(z + (((unsigned)i) << 6) + coff); }
        if (e + 3 < end) { int i = csr8[e + 3].x; s3 = sc[i]; u3 = *(const uint2*)(z + (((unsigned)i) << 6) + coff); }
        if (e + 4 < end) { int i = csr8[e + 4].x; s4 = sc[i]; u4 = *(const uint2*)(z + (((unsigned)i) << 6) + coff); }
        if (e + 5 < end) { int i = csr8[e + 5].x; s5 = sc[i]; u5 = *(const uint2*)(z + (((unsigned)i) << 6) + coff); }
        if (e + 6 < end) { int i = csr8[e + 6].x; s6 = sc[i]; u6 = *(const uint2*)(z + (((unsigned)i) << 6) + coff); }
        if (e + 7 < end) { int i = csr8[e + 7].x; s7 = sc[i]; u7 = *(const uint2*)(z + (((unsigned)i) << 6) + coff); }
        ssum += ((s0 + s1) + (s2 + s3)) + ((s4 + s5) + (s6 + s7));
        acc8(s0, u0, a); acc8(s1, u1, a); acc8(s2, u2, a); acc8(s3, u3, a);
        acc8(s4, u4, a); acc8(s5, u5, a); acc8(s6, u6, a); acc8(s7, u7, a);
        e += 8;
    }

    {
        float base = 128.f * ssum;
        float inv = 1.0f / (float)(end - beg + 1);
        float4 b0 = ((const float4*)bias)[c * 2];
        float4 b1v = ((const float4*)bias)[c * 2 + 1];
        out[(long)node * 16 + c * 2] =
            make_float4((a[0] - base) * inv + b0.x, (a[1] - base) * inv + b0.y,
                        (a[2] - base) * inv + b0.z, (a[3] - base) * inv + b0.w);
        out[(long)node * 16 + c * 2 + 1] =
            make_float4((a[4] - base) * inv + b1v.x, (a[5] - base) * inv + b1v.y,
                        (a[6] - base) * inv + b1v.z, (a[7] - base) * inv + b1v.w);
    }
}

extern "C" void kernel_launch(void* const* d_in, const int* in_sizes, int n_in,
                              void* d_out, int out_size, void* d_ws, size_t ws_size,
                              hipStream_t stream) {
    const float* feat = (const float*)d_in[0];
    const float* W1   = (const float*)d_in[1];
    const float* b1   = (const float*)d_in[2];
    const float* W2   = (const float*)d_in[3];
    const float* b2   = (const float*)d_in[4];
    const int*   src  = (const int*)d_in[5];
    const int*   dst  = (const int*)d_in[6];
    float* out = (float*)d_out;

    // Workspace layout:
    //   bcur i32[782]            @ 0x0000000
    //   begs i32[100000]         @ 0x0001000
    //   ends i32[100000]         @ 0x0063000
    //   ebuf i32[NB*CAP]         @ 0x00C5000  (8.0 MB)
    //   csr8 int2[NB*CAP]        @ 0x0900000  (16.0 MB)
    //   z1   u8 [12.8M]          @ 0x1900000
    //   sc1  f32[100000]         @ 0x2600000
    //   h1   f16[12.8M]          @ 0x2700000  (25.6 MB)
    //   z2   u8 [6.4M]           @ 0x4100000
    //   sc2  f32[100000]         @ 0x4800000
    //   W1t  f16[16384]          @ 0x4900000
    //   W2t  f16[8192]           @ 0x4910000
    char* ws = (char*)d_ws;
    int* bcur = (int*)(ws + 0x0000000);
    int* begs = (int*)(ws + 0x0001000);
    int* ends = (int*)(ws + 0x0063000);
    int* ebuf = (int*)(ws + 0x00C5000);
    int2* csr8 = (int2*)(ws + 0x0900000);
    unsigned char* z1 = (unsigned char*)(ws + 0x1900000);
    float* sc1 = (float*)(ws + 0x2600000);
    f16* h1   = (f16*)(ws + 0x2700000);
    unsigned char* z2 = (unsigned char*)(ws + 0x4100000);
    float* sc2 = (float*)(ws + 0x4800000);
    f16* W1t  = (f16*)(ws + 0x4900000);
    f16* W2t  = (f16*)(ws + 0x4910000);

    // 1. init cursors + weight prep (no memsets needed anywhere)
    init_k<<<100, 256, 0, stream>>>(bcur, W1, W1t, W2, W2t);

    // 2. edge scatter into padded buckets + layer-1 GEMM (fused)
    scatter_gemm1<<<EBLOCKS + GEMM_BLOCKS, 256, 0, stream>>>(src, dst, bcur, ebuf,
                                                             feat, W1t, z1, sc1);

    // 3. per-bucket CSR fill ({src,sc1} csr8) + per-node beg/end
    fill_bucket<<<NB, 256, 0, stream>>>(ebuf, bcur, sc1, begs, ends, csr8);

    // 4. layer-1 gather (+bias+relu) -> h1, barrier-free small blocks
    gather128_h1<<<NNODES / 16, 256, 0, stream>>>(z1, sc1, csr8, begs, ends,
                                                  b1, h1);

    // 5. layer-2 projection: z2 = int8(h1 @ W2t^T) + sc2
    gemm2_k<<<GEMM_BLOCKS, 256, 0, stream>>>(h1, W2t, z2, sc2);

    // 6. layer-2 gather (+bias) -> output; 32 nodes/block, 3125*32 = 100000
    gather64<<<3125, 256, 0, stream>>>(z2, sc2, csr8, begs, ends, b2,
                                       (float4*)out);
}